// Round 8
// baseline (383.280 us; speedup 1.0000x reference)
//
#include <hip/hip_runtime.h>
#include <hip/hip_bf16.h>

typedef __attribute__((ext_vector_type(8))) short short8;
typedef __attribute__((ext_vector_type(8))) unsigned short ushort8;
typedef __attribute__((ext_vector_type(4))) float floatx4;

#define AS_STRIDE 72   // 64 cin + 8 pad, BAKED INTO xpad (round 8)

// ws layout: [0, 1179648) kerF (1024x576 bf16, fragment order)
//            [1179648, +10040320) xpad bf16 [16][66][66][72] (pad baked in,
//            +4KB slack for the uniform 40960B window over-read)
#define KERF_BYTES (1024 * 576 * 2)
#define XPAD_PIX (16 * 66 * 66)          // 69696 padded pixels
#define XPAD_SEGS (XPAD_PIX * 9)         // 627264 16B segments

// ---------------------------------------------------------------------------
// Prep kernel:
//  blocks 0..71     : sample kernels -> kerF in MFMA B-fragment order.
//  blocks 72..2522  : xpad = bf16(x), zero spatial border, 8-elem channel pad
//                     (seg 8) baked in so conv can global_load_lds linearly.
// Fragment cout mapping: co = (nz>>2)*64 + lane15*4 + (nz&3) (dense stores).
// ---------------------------------------------------------------------------
__global__ void prep_k(const float* __restrict__ x,
                       const float* __restrict__ mu,
                       const float* __restrict__ logstd,
                       const float* __restrict__ noise,
                       __hip_bfloat16* __restrict__ kerF,
                       __hip_bfloat16* __restrict__ xpad) {
  const int bx = blockIdx.x;
  const int tid = threadIdx.x;
  if (bx >= 72) {
    int i = (bx - 72) * 256 + tid;            // segment index
    if (i < XPAD_SEGS) {
      int pixel = i / 9, seg = i - (i / 9) * 9;
      int b = pixel / 4356;                   // 66*66
      int rem = pixel - b * 4356;
      int hp = rem / 66, wp = rem - (rem / 66) * 66;
      int h = hp - 1, w = wp - 1;
      ushort8 val = {0, 0, 0, 0, 0, 0, 0, 0};
      if (seg < 8 && (unsigned)h < 64u && (unsigned)w < 64u) {
        const float* src = x + ((((size_t)b * 64 + h) * 64 + w) << 6) + (seg << 3);
        float4 v0 = *(const float4*)src;
        float4 v1 = *(const float4*)(src + 4);
        val[0] = __bfloat16_as_ushort(__float2bfloat16(v0.x));
        val[1] = __bfloat16_as_ushort(__float2bfloat16(v0.y));
        val[2] = __bfloat16_as_ushort(__float2bfloat16(v0.z));
        val[3] = __bfloat16_as_ushort(__float2bfloat16(v0.w));
        val[4] = __bfloat16_as_ushort(__float2bfloat16(v1.x));
        val[5] = __bfloat16_as_ushort(__float2bfloat16(v1.y));
        val[6] = __bfloat16_as_ushort(__float2bfloat16(v1.z));
        val[7] = __bfloat16_as_ushort(__float2bfloat16(v1.w));
      }
      *(ushort8*)(xpad + (size_t)i * 8) = val;   // elem off = pixel*72 + seg*8
    }
  } else {
    // ---- sample: kerF[((s*18 + tap*2 + khalf)*8 + nz)*64 + lane][8] ----
    const int s = bx / 9, tap = bx % 9;
    const float* mu_p = mu + tap * 8192;      // [ci][co]
    const float* ls_p = logstd + tap * 8192;
    const float* nz_p = noise + (s * 9 + tap) * 8192;
    for (int f = tid; f < 1024; f += 256) {   // f = khalf*512 + nz*64 + lane
      int khalf = f >> 9;
      int nz = (f >> 6) & 7;
      int lane = f & 63;
      int co = ((nz >> 2) << 6) + (lane & 15) * 4 + (nz & 3);  // DENSE mapping
      int ci0 = khalf * 32 + ((lane >> 4) & 3) * 8;
      short8 frag;
#pragma unroll
      for (int j = 0; j < 8; ++j) {
        int idx = (ci0 + j) * 128 + co;
        float v = mu_p[idx] + nz_p[idx] * expf(ls_p[idx]);
        frag[j] = (short)__bfloat16_as_ushort(__float2bfloat16(v));
      }
      *(short8*)(kerF + ((size_t)((s * 18 + tap * 2 + khalf) * 8 + nz) * 64 + lane) * 8) = frag;
    }
  }
}

__device__ inline void gll16(const void* g, void* l) {
  __builtin_amdgcn_global_load_lds(
      (const __attribute__((address_space(1))) unsigned int*)g,
      (__attribute__((address_space(3))) unsigned int*)l, 16, 0, 0);
}

// ---------------------------------------------------------------------------
// Conv + ELU, implicit GEMM. Tile = 128 pixels (2 rows x 64 w) x 128 n.
// 4 waves x (4x4 MFMA 16x16x32 bf16). Persistent: 1024 blocks x 4 tiles,
// n_tile fixed per block (B panel XCD/L2-local).
// Round 8:
//  (a) A staged via global_load_lds (xpad pre-padded -> linear 38KB window),
//      issued right after the read-barrier so it lands DURING the epilogue
//      (stage moved off the serial critical path; no VGPR round trip).
//  (b) 3-slot B pipeline: every B fragment issued ~2 mfmaSteps (~260-520cy)
//      before use, covering L2 latency (~200cy). Period-3 static rotation.
// ---------------------------------------------------------------------------
__global__ __launch_bounds__(256, 3)
void conv_elu_k(const __hip_bfloat16* __restrict__ xpad,
                const __hip_bfloat16* __restrict__ kerF,
                float* __restrict__ out) {
  __shared__ __hip_bfloat16 As[20480];   // 40960 B (38016 used + slack)

  const int tid = threadIdx.x;
  const int lane = tid & 63;
  const int lane15 = tid & 15;
  const int quad = (tid >> 4) & 3;
  const int wave = tid >> 6;
  const int n_tile = blockIdx.x & 7;     // 0..7 (= sample s), fixed per block
  const int mt_base = blockIdx.x >> 3;   // 0..127

  const int row_sel = wave >> 1;
  const int nz0sel = wave & 1;

  const __hip_bfloat16* bBase =
      kerF + (size_t)n_tile * 18 * 8 * 64 * 8 + (nz0sel << 2) * 512 + lane * 8;
  const __hip_bfloat16* aRowBase =
      As + (row_sel * 66 + lane15) * AS_STRIDE + quad * 8;

  short8 aE[4], aO[4], bA[4], bB[4], bC[4];

  auto loadB = [&](short8* dst, const __hip_bfloat16* p) {
#pragma unroll
    for (int ni = 0; ni < 4; ++ni)
      dst[ni] = *(const short8*)(p + ni * 512);
  };
  auto loadA = [&](short8* dst, const __hip_bfloat16* row, int khalfOff) {
#pragma unroll
    for (int mi = 0; mi < 4; ++mi)
      dst[mi] = *(const short8*)(row + khalfOff + mi * 16 * AS_STRIDE);
  };

  // Stage tile `it`'s A window: 2560 uniform 16B chunks (40960 B incl slack).
  auto stage = [&](int it) {
    const int mtN = mt_base + (it << 7);
    const int bN = mtN >> 5;
    const int h0N = (mtN & 31) << 1;
    const __hip_bfloat16* g = xpad + (size_t)((bN * 66 + h0N) * 66) * AS_STRIDE;
#pragma unroll
    for (int c0 = 0; c0 < 2560; c0 += 256) {
      int c = c0 + tid;
      gll16(g + (size_t)c * 8, (void*)(As + (size_t)(c0 + (tid & 192)) * 8));
    }
  };

  stage(0);

#pragma unroll 1
  for (int it = 0; it < 4; ++it) {
    const int mt = mt_base + (it << 7);
    const int b = mt >> 5;
    const int h0 = (mt & 31) << 1;

    __syncthreads();   // staged A (vmcnt drained) visible to all waves

    floatx4 acc[4][4] = {};
    const __hip_bfloat16* bPtr = bBase;
    const __hip_bfloat16* aRow = aRowBase;
    int kw = 0;

    auto mfmaStep = [&](short8 (&a)[4], short8 (&bb)[4]) {
#pragma unroll
      for (int mi = 0; mi < 4; ++mi)
#pragma unroll
        for (int ni = 0; ni < 4; ++ni)
          acc[mi][ni] = __builtin_amdgcn_mfma_f32_16x16x32_bf16(
              a[mi], bb[ni], acc[mi][ni], 0, 0, 0);
    };

    // TAP: process one 3x3 tap (2 khalves). Entering: bEv=B[2t], bOd=B[2t+1].
    // Loads B[2t+2] into bNx and B[2t+3] into bEv (freed mid-tap).
    auto TAP = [&](short8 (&bEv)[4], short8 (&bOd)[4], short8 (&bNx)[4],
                   bool last) {
      if (!last) loadB(bNx, bPtr + 8192);       // B[2t+2], 2-step lead
      loadA(aO, aRow, 32);
      mfmaStep(aE, bEv);
      bPtr += 8192;
      aRow += AS_STRIDE;
      if (++kw == 3) { kw = 0; aRow += 63 * AS_STRIDE; }
      if (!last) {
        loadB(bEv, bPtr + 4096);                // B[2t+3], 2-step lead
        loadA(aE, aRow, 0);
      }
      mfmaStep(aO, bOd);
    };

    loadB(bA, bPtr);              // B[0]
    loadB(bB, bPtr + 4096);       // B[1]
    loadA(aE, aRow, 0);
#pragma unroll 1
    for (int t3 = 0; t3 < 3; ++t3) {
      TAP(bA, bB, bC, false);
      TAP(bC, bA, bB, false);
      TAP(bB, bC, bA, t3 == 2);
    }

    __syncthreads();   // all waves done reading As

    if (it < 3) stage(it + 1);   // fire-and-forget; lands during epilogue

    // ---- Epilogue: ELU + dense float4 stores (wave-contiguous 256B rows) ----
    const int h = h0 + row_sel;
    float* outp = out + (size_t)((b * 64 + h) * 64) * 1024 +
                  (size_t)(n_tile * 128 + (nz0sel << 6) + (lane15 << 2));
#pragma unroll
    for (int mi = 0; mi < 4; ++mi) {
#pragma unroll
      for (int r = 0; r < 4; ++r) {
        int w = mi * 16 + quad * 4 + r;
        float4 v;
        float e0 = acc[mi][0][r];
        float e1 = acc[mi][1][r];
        float e2 = acc[mi][2][r];
        float e3 = acc[mi][3][r];
        v.x = e0 > 0.f ? e0 : __expf(e0) - 1.f;
        v.y = e1 > 0.f ? e1 : __expf(e1) - 1.f;
        v.z = e2 > 0.f ? e2 : __expf(e2) - 1.f;
        v.w = e3 > 0.f ? e3 : __expf(e3) - 1.f;
        *(float4*)(outp + (size_t)w * 1024) = v;
      }
    }
  }
}

extern "C" void kernel_launch(void* const* d_in, const int* in_sizes, int n_in,
                              void* d_out, int out_size, void* d_ws, size_t ws_size,
                              hipStream_t stream) {
  const float* x      = (const float*)d_in[0];
  const float* mu     = (const float*)d_in[1];
  const float* logstd = (const float*)d_in[2];
  const float* noise  = (const float*)d_in[3];
  float* out = (float*)d_out;
  __hip_bfloat16* kerF = (__hip_bfloat16*)d_ws;
  __hip_bfloat16* xpad = (__hip_bfloat16*)((char*)d_ws + KERF_BYTES);

  prep_k<<<72 + 2451, 256, 0, stream>>>(x, mu, logstd, noise, kerF, xpad);
  conv_elu_k<<<1024, 256, 0, stream>>>(xpad, kerF, out);
}

// Round 9
// 341.160 us; speedup vs baseline: 1.1235x; 1.1235x over previous
//
#include <hip/hip_runtime.h>
#include <hip/hip_bf16.h>

typedef __attribute__((ext_vector_type(8))) short short8;
typedef __attribute__((ext_vector_type(8))) unsigned short ushort8;
typedef __attribute__((ext_vector_type(4))) float floatx4;

#define AS_STRIDE 72   // 64 cin + 8 pad -> 16B-aligned b128

// ws layout: [0, 1179648) kerF (1024x576 bf16, fragment order)
//            [1179648, +8921088) xpad bf16 [16][66][66][64], zero borders
#define KERF_BYTES (1024 * 576 * 2)

// ---------------------------------------------------------------------------
// Prep kernel (fused):
//  blocks 0..71   : sample kernels -> kerF in MFMA B-fragment order.
//  blocks 72..2249: build xpad = bf16(x) zero-padded to 66x66 spatially.
// Fragment cout mapping: co = (nz>>2)*64 + lane15*4 + (nz&3).
// -> a wave (nz0 fixed) owns 64 contiguous cout; epilogue float4 stores are
//    fully dense per wave (256 B contiguous per output row).
// ---------------------------------------------------------------------------
__global__ void prep_k(const float* __restrict__ x,
                       const float* __restrict__ mu,
                       const float* __restrict__ logstd,
                       const float* __restrict__ noise,
                       __hip_bfloat16* __restrict__ kerF,
                       __hip_bfloat16* __restrict__ xpad) {
  const int bx = blockIdx.x;
  const int tid = threadIdx.x;
  if (bx >= 72) {
    // ---- xpad: i indexes 8-channel segments of padded rows ----
    int i = (bx - 72) * 256 + tid;            // < 557568 = 16*66*66*8
    int row = i >> 3, seg = i & 7;            // row < 69696
    int b = row / 4356;                       // 66*66
    int rem = row - b * 4356;
    int hp = rem / 66, wp = rem - (rem / 66) * 66;
    int h = hp - 1, w = wp - 1;
    ushort8 val = {0, 0, 0, 0, 0, 0, 0, 0};
    if ((unsigned)h < 64u && (unsigned)w < 64u) {
      const float* src = x + ((((size_t)b * 64 + h) * 64 + w) << 6) + (seg << 3);
      float4 v0 = *(const float4*)src;
      float4 v1 = *(const float4*)(src + 4);
      val[0] = __bfloat16_as_ushort(__float2bfloat16(v0.x));
      val[1] = __bfloat16_as_ushort(__float2bfloat16(v0.y));
      val[2] = __bfloat16_as_ushort(__float2bfloat16(v0.z));
      val[3] = __bfloat16_as_ushort(__float2bfloat16(v0.w));
      val[4] = __bfloat16_as_ushort(__float2bfloat16(v1.x));
      val[5] = __bfloat16_as_ushort(__float2bfloat16(v1.y));
      val[6] = __bfloat16_as_ushort(__float2bfloat16(v1.z));
      val[7] = __bfloat16_as_ushort(__float2bfloat16(v1.w));
    }
    *(ushort8*)(xpad + ((size_t)row << 6) + (seg << 3)) = val;
  } else {
    // ---- sample: kerF[((s*18 + tap*2 + khalf)*8 + nz)*64 + lane][8] ----
    // lane holds B[k=khalf*32+((lane>>4)&3)*8+j][co=(nz>>2)*64+(lane&15)*4+(nz&3)]
    const int s = bx / 9, tap = bx % 9;
    const float* mu_p = mu + tap * 8192;      // [ci][co]
    const float* ls_p = logstd + tap * 8192;
    const float* nz_p = noise + (s * 9 + tap) * 8192;
    for (int f = tid; f < 1024; f += 256) {   // f = khalf*512 + nz*64 + lane
      int khalf = f >> 9;
      int nz = (f >> 6) & 7;
      int lane = f & 63;
      int co = ((nz >> 2) << 6) + (lane & 15) * 4 + (nz & 3);  // DENSE mapping
      int ci0 = khalf * 32 + ((lane >> 4) & 3) * 8;
      short8 frag;
#pragma unroll
      for (int j = 0; j < 8; ++j) {
        int idx = (ci0 + j) * 128 + co;
        float v = mu_p[idx] + nz_p[idx] * expf(ls_p[idx]);
        frag[j] = (short)__bfloat16_as_ushort(__float2bfloat16(v));
      }
      *(short8*)(kerF + ((size_t)((s * 18 + tap * 2 + khalf) * 8 + nz) * 64 + lane) * 8) = frag;
    }
  }
}

// ---------------------------------------------------------------------------
// Conv + ELU, implicit GEMM. Tile = 128 pixels (2 rows x 64 w) x 128 n.
// 4 waves x (4x4 MFMA 16x16x32 bf16). B from global (XCD-local L2).
// Persistent-ish grid: 1024 blocks x 4 tiles, n_tile fixed per block.
// Round 9: exact revert to the round-6 variant (best measured, 341.9us).
// Session evidence: 6 schedule variants all 342+-2; NT stores +56, f32
// staging +25, prepad/gll_lds +41 -> conv is at its traffic/overlap floor;
// remaining time is harness fills (~220us) + prep (~12us) + conv (~110us).
// ---------------------------------------------------------------------------
__global__ __launch_bounds__(256, 3)
void conv_elu_k(const __hip_bfloat16* __restrict__ xpad,
                const __hip_bfloat16* __restrict__ kerF,
                float* __restrict__ out) {
  __shared__ __hip_bfloat16 As[4 * 66 * AS_STRIDE];  // 38016 B

  const int tid = threadIdx.x;
  const int lane = tid & 63;
  const int lane15 = tid & 15;
  const int quad = (tid >> 4) & 3;
  const int wave = tid >> 6;
  const int n_tile = blockIdx.x & 7;     // 0..7 (= sample s = XCD id), fixed
  const int mt_base = blockIdx.x >> 3;   // 0..127

  const int row_sel = wave >> 1;         // which of the 2 output rows
  const int nz0sel = wave & 1;           // fragment nz half (0 or 1)

  // Invariant per block:
  const __hip_bfloat16* bBase =
      kerF + (size_t)n_tile * 18 * 8 * 64 * 8 + (nz0sel << 2) * 512 + lane * 8;
  const __hip_bfloat16* aRowBase =
      As + (row_sel * 66 + lane15) * AS_STRIDE + quad * 8;

  short8 aE[4], aO[4], bE[4], bO[4];

  auto loadB = [&](short8* dst, const __hip_bfloat16* p) {
#pragma unroll
    for (int ni = 0; ni < 4; ++ni)
      dst[ni] = *(const short8*)(p + ni * 512);
  };
  auto loadA = [&](short8* dst, const __hip_bfloat16* row, int khalfOff) {
#pragma unroll
    for (int mi = 0; mi < 4; ++mi)
      dst[mi] = *(const short8*)(row + khalfOff + mi * 16 * AS_STRIDE);
  };

#pragma unroll 1
  for (int it = 0; it < 4; ++it) {
    const int mt = mt_base + (it << 7);  // 0..511
    const int b = mt >> 5;
    const int h0 = (mt & 31) << 1;

    // ---- Stage A: xpad rows h0..h0+3 (contiguous), 16B loads ----
    const __hip_bfloat16* xbase = xpad + (((size_t)(b * 66 + h0) * 66) << 6);
    for (int c = tid; c < 2112; c += 256) {      // 2112 x 16B = 33792 B
      ushort8 v = *(const ushort8*)(xbase + ((size_t)c << 3));
      int r = c / 528;                           // 528 chunks per padded row
      int cc = c - r * 528;
      int j = cc >> 3;
      int ci = (cc & 7) << 3;
      *(ushort8*)&As[(r * 66 + j) * AS_STRIDE + ci] = v;
    }

    floatx4 acc[4][4] = {};
    const __hip_bfloat16* bPtr = bBase;
    const __hip_bfloat16* aRow = aRowBase;

    __syncthreads();  // A ready

    auto mfmaStep = [&](short8 (&a)[4], short8 (&bb)[4]) {
#pragma unroll
      for (int mi = 0; mi < 4; ++mi)
#pragma unroll
        for (int ni = 0; ni < 4; ++ni)
          acc[mi][ni] = __builtin_amdgcn_mfma_f32_16x16x32_bf16(
              a[mi], bb[ni], acc[mi][ni], 0, 0, 0);
    };

    loadB(bE, bPtr);
    loadA(aE, aRow, 0);
    int kw = 0;
#pragma unroll 1
    for (int tap = 0; tap < 8; ++tap) {
      loadB(bO, bPtr + 4096);            // odd khalf of this tap
      loadA(aO, aRow, 32);
      mfmaStep(aE, bE);
      bPtr += 8192;                      // advance to next tap
      aRow += AS_STRIDE;
      if (++kw == 3) { kw = 0; aRow += 63 * AS_STRIDE; }
      loadB(bE, bPtr);                   // even khalf of next tap
      loadA(aE, aRow, 0);
      mfmaStep(aO, bO);
    }
    loadB(bO, bPtr + 4096);              // tap 8, odd khalf
    loadA(aO, aRow, 32);
    mfmaStep(aE, bE);
    mfmaStep(aO, bO);

    // ---- Epilogue: ELU + dense float4 stores.
    // co = nz0sel*64 + lane15*4 + ni -> wave writes 256 B contiguous/row ----
    const int h = h0 + row_sel;
    float* outp = out + (size_t)((b * 64 + h) * 64) * 1024 +
                  (size_t)(n_tile * 128 + (nz0sel << 6) + (lane15 << 2));
#pragma unroll
    for (int mi = 0; mi < 4; ++mi) {
#pragma unroll
      for (int r = 0; r < 4; ++r) {
        int w = mi * 16 + quad * 4 + r;
        float4 v;
        float e0 = acc[mi][0][r];
        float e1 = acc[mi][1][r];
        float e2 = acc[mi][2][r];
        float e3 = acc[mi][3][r];
        v.x = e0 > 0.f ? e0 : __expf(e0) - 1.f;
        v.y = e1 > 0.f ? e1 : __expf(e1) - 1.f;
        v.z = e2 > 0.f ? e2 : __expf(e2) - 1.f;
        v.w = e3 > 0.f ? e3 : __expf(e3) - 1.f;
        *(float4*)(outp + (size_t)w * 1024) = v;
      }
    }

    if (it < 3) __syncthreads();  // all waves done reading As before re-stage
  }
}

extern "C" void kernel_launch(void* const* d_in, const int* in_sizes, int n_in,
                              void* d_out, int out_size, void* d_ws, size_t ws_size,
                              hipStream_t stream) {
  const float* x      = (const float*)d_in[0];
  const float* mu     = (const float*)d_in[1];
  const float* logstd = (const float*)d_in[2];
  const float* noise  = (const float*)d_in[3];
  float* out = (float*)d_out;
  __hip_bfloat16* kerF = (__hip_bfloat16*)d_ws;
  __hip_bfloat16* xpad = (__hip_bfloat16*)((char*)d_ws + KERF_BYTES);

  prep_k<<<2250, 256, 0, stream>>>(x, mu, logstd, noise, kerF, xpad);
  conv_elu_k<<<1024, 256, 0, stream>>>(xpad, kerF, out);
}